// Round 1
// baseline (592.933 us; speedup 1.0000x reference)
//
#include <hip/hip_runtime.h>
#include <hip/hip_bf16.h>

typedef __attribute__((ext_vector_type(8))) __bf16 bf16x8;
typedef __attribute__((ext_vector_type(4))) __bf16 bf16x4;
typedef __attribute__((ext_vector_type(4))) float f32x4;

#define AS1(p) ((__attribute__((address_space(1))) void*)(p))
#define AS3(p) ((__attribute__((address_space(3))) void*)(p))

// ---------------------------------------------------------------- f32 -> bf16
__global__ void f2b_kernel(const float4* __restrict__ in, bf16x4* __restrict__ out, int n4) {
    int idx = blockIdx.x * blockDim.x + threadIdx.x;
    int stride = gridDim.x * blockDim.x;
    for (int i = idx; i < n4; i += stride) {
        float4 v = in[i];
        bf16x4 o;
        o[0] = (__bf16)v.x; o[1] = (__bf16)v.y; o[2] = (__bf16)v.z; o[3] = (__bf16)v.w;
        out[i] = o;
    }
}

// ---------------------------------------------------------------- GEMM C = A @ B^T
// A[M][K] bf16, Bw[N][K] bf16 row-major. 128x128 tile, BK=32, 256 thr (4 waves, 2x2).
// Cf != nullptr -> fp32 out (+bias); else bf16 out to Cb.
__global__ __launch_bounds__(256)
void gemm_bt(const __bf16* __restrict__ A, const __bf16* __restrict__ Bw,
             const float* __restrict__ bias, float* __restrict__ Cf,
             __bf16* __restrict__ Cb, int M, int N, int K)
{
    __shared__ __bf16 As[128 * 32];
    __shared__ __bf16 Bs[128 * 32];
    const int tid = threadIdx.x;
    const int l = tid & 63, w = tid >> 6;
    const int m0 = blockIdx.y * 128, n0 = blockIdx.x * 128;
    const int wr = (w >> 1) * 64, wc = (w & 1) * 64;
    const int fr = l & 15, koff = (l >> 4) * 8;

    f32x4 acc[4][4] = {};

    const int c0 = tid, c1 = tid + 256;
    const __bf16* Ab = A + m0 * K;
    const __bf16* Bb = Bw + n0 * K;
    // per-chunk global offsets (row = c>>2, 16B piece = c&3)
    const int ga0 = (c0 >> 2) * K + (c0 & 3) * 8;
    const int ga1 = (c1 >> 2) * K + (c1 & 3) * 8;

    for (int k0 = 0; k0 < K; k0 += 32) {
        __builtin_amdgcn_global_load_lds(AS1(Ab + ga0 + k0), AS3(As + c0 * 8), 16, 0, 0);
        __builtin_amdgcn_global_load_lds(AS1(Ab + ga1 + k0), AS3(As + c1 * 8), 16, 0, 0);
        __builtin_amdgcn_global_load_lds(AS1(Bb + ga0 + k0), AS3(Bs + c0 * 8), 16, 0, 0);
        __builtin_amdgcn_global_load_lds(AS1(Bb + ga1 + k0), AS3(Bs + c1 * 8), 16, 0, 0);
        __syncthreads();

        bf16x8 af[4], bfv[4];
        #pragma unroll
        for (int m = 0; m < 4; ++m)
            af[m] = *(const bf16x8*)&As[(wr + m * 16 + fr) * 32 + koff];
        #pragma unroll
        for (int n = 0; n < 4; ++n)
            bfv[n] = *(const bf16x8*)&Bs[(wc + n * 16 + fr) * 32 + koff];
        #pragma unroll
        for (int m = 0; m < 4; ++m)
            #pragma unroll
            for (int n = 0; n < 4; ++n)
                acc[m][n] = __builtin_amdgcn_mfma_f32_16x16x32_bf16(af[m], bfv[n], acc[m][n], 0, 0, 0);
        __syncthreads();
    }

    // epilogue: C/D layout col = l&15, row = (l>>4)*4 + r
    #pragma unroll
    for (int m = 0; m < 4; ++m) {
        #pragma unroll
        for (int n = 0; n < 4; ++n) {
            const int row = m0 + wr + m * 16 + (l >> 4) * 4;
            const int col = n0 + wc + n * 16 + fr;
            const float bv = bias ? bias[col] : 0.0f;
            #pragma unroll
            for (int r = 0; r < 4; ++r) {
                float v = acc[m][n][r] + bv;
                if (Cf) Cf[(row + r) * N + col] = v;
                else    Cb[(row + r) * N + col] = (__bf16)v;
            }
        }
    }
}

// ---------------------------------------------------------------- RMSNorm on q,k (in place)
// qkv [16384][3072]; cols 0..1023 = q (scale folded), 1024..2047 = k.
__global__ __launch_bounds__(256)
void rmsnorm_kernel(__bf16* __restrict__ qkv, const float* __restrict__ qw,
                    const float* __restrict__ kw)
{
    const int row = blockIdx.x;
    const int t = threadIdx.x;
    const int g = t >> 3, j = t & 7;        // 32 groups of 64 elems, 8 lanes each
    const int part = g >> 4, head = g & 15; // part 0 = q, 1 = k
    const int base = row * 3072 + part * 1024 + head * 64 + j * 8;
    bf16x8 v = *(const bf16x8*)&qkv[base];
    float s = 0.0f;
    #pragma unroll
    for (int i = 0; i < 8; ++i) { float f = (float)v[i]; s += f * f; }
    s += __shfl_xor(s, 1); s += __shfl_xor(s, 2); s += __shfl_xor(s, 4);
    float r = rsqrtf(s * (1.0f / 64.0f) + 1e-6f);
    if (part == 0) r *= 0.125f;             // Dh^-0.5 folded into q
    const float* wp = (part == 0) ? qw : kw;
    bf16x8 o;
    #pragma unroll
    for (int i = 0; i < 8; ++i) o[i] = (__bf16)((float)v[i] * r * wp[j * 8 + i]);
    *(bf16x8*)&qkv[base] = o;
}

// ---------------------------------------------------------------- flash attention
// grid (16 qblocks, 16 heads, 16 batch), 256 thr. Each wave: 16 q-rows.
// K read from global (L2-resident); V staged transposed in LDS; P via per-wave LDS.
__global__ __launch_bounds__(256)
void attn_kernel(const __bf16* __restrict__ qkv, __bf16* __restrict__ ao)
{
    __shared__ __bf16 Vt[64 * 64];       // Vt[d][key]
    __shared__ __bf16 Pl[4 * 16 * 64];   // per-wave P[qrow][key]
    const int tid = threadIdx.x, l = tid & 63, w = tid >> 6;
    const int b = blockIdx.z, h = blockIdx.y, qb = blockIdx.x;
    const int fr = l & 15, fk = l >> 4;
    const int koff = fk * 8;

    const int qrow0 = b * 1024 + qb * 64 + w * 16;
    bf16x8 qf[2];
    #pragma unroll
    for (int dc = 0; dc < 2; ++dc)
        qf[dc] = *(const bf16x8*)&qkv[(qrow0 + fr) * 3072 + h * 64 + dc * 32 + koff];

    float m_r[4], ls[4];
    f32x4 oacc[4] = {};
    #pragma unroll
    for (int r = 0; r < 4; ++r) { m_r[r] = -1e30f; ls[r] = 0.0f; }

    const int key_t = tid >> 2, dgrp = tid & 3;

    for (int kt = 0; kt < 16; ++kt) {
        __syncthreads();
        // stage V transposed
        {
            const int vbase = (b * 1024 + kt * 64 + key_t) * 3072 + 2048 + h * 64 + dgrp * 16;
            bf16x8 v0 = *(const bf16x8*)&qkv[vbase];
            bf16x8 v1 = *(const bf16x8*)&qkv[vbase + 8];
            #pragma unroll
            for (int j = 0; j < 8; ++j) {
                Vt[(dgrp * 16 + j) * 64 + key_t] = v0[j];
                Vt[(dgrp * 16 + 8 + j) * 64 + key_t] = v1[j];
            }
        }
        __syncthreads();

        // S = Q @ K^T  (scale already folded into q)
        f32x4 sacc[4] = {};
        #pragma unroll
        for (int n = 0; n < 4; ++n) {
            #pragma unroll
            for (int dc = 0; dc < 2; ++dc) {
                bf16x8 kf = *(const bf16x8*)&qkv[(b * 1024 + kt * 64 + n * 16 + fr) * 3072
                                                 + 1024 + h * 64 + dc * 32 + koff];
                sacc[n] = __builtin_amdgcn_mfma_f32_16x16x32_bf16(qf[dc], kf, sacc[n], 0, 0, 0);
            }
        }

        // online softmax (rows live on (l>>4)*4 + r across lanes fr = key)
        float tm[4], mnew[4], resc[4], psum[4];
        #pragma unroll
        for (int r = 0; r < 4; ++r)
            tm[r] = fmaxf(fmaxf(sacc[0][r], sacc[1][r]), fmaxf(sacc[2][r], sacc[3][r]));
        #pragma unroll
        for (int mask = 1; mask <= 8; mask <<= 1)
            #pragma unroll
            for (int r = 0; r < 4; ++r)
                tm[r] = fmaxf(tm[r], __shfl_xor(tm[r], mask));
        #pragma unroll
        for (int r = 0; r < 4; ++r) {
            mnew[r] = fmaxf(m_r[r], tm[r]);
            resc[r] = __expf(m_r[r] - mnew[r]);
            m_r[r] = mnew[r];
            psum[r] = 0.0f;
        }
        #pragma unroll
        for (int n = 0; n < 4; ++n)
            #pragma unroll
            for (int r = 0; r < 4; ++r) {
                float p = __expf(sacc[n][r] - mnew[r]);
                psum[r] += p;
                Pl[(w * 16 + fk * 4 + r) * 64 + n * 16 + fr] = (__bf16)p;
            }
        #pragma unroll
        for (int mask = 1; mask <= 8; mask <<= 1)
            #pragma unroll
            for (int r = 0; r < 4; ++r)
                psum[r] += __shfl_xor(psum[r], mask);
        #pragma unroll
        for (int r = 0; r < 4; ++r)
            ls[r] = ls[r] * resc[r] + psum[r];
        #pragma unroll
        for (int nd = 0; nd < 4; ++nd)
            #pragma unroll
            for (int r = 0; r < 4; ++r)
                oacc[nd][r] *= resc[r];

        // O += P @ V
        #pragma unroll
        for (int nd = 0; nd < 4; ++nd)
            #pragma unroll
            for (int kc = 0; kc < 2; ++kc) {
                bf16x8 pf = *(const bf16x8*)&Pl[(w * 16 + fr) * 64 + kc * 32 + koff];
                bf16x8 vf = *(const bf16x8*)&Vt[(nd * 16 + fr) * 64 + kc * 32 + koff];
                oacc[nd] = __builtin_amdgcn_mfma_f32_16x16x32_bf16(pf, vf, oacc[nd], 0, 0, 0);
            }
    }

    #pragma unroll
    for (int nd = 0; nd < 4; ++nd)
        #pragma unroll
        for (int r = 0; r < 4; ++r) {
            const int row = qrow0 + fk * 4 + r;
            ao[row * 1024 + h * 64 + nd * 16 + fr] = (__bf16)(oacc[nd][r] / ls[r]);
        }
}

// ---------------------------------------------------------------- launch
extern "C" void kernel_launch(void* const* d_in, const int* in_sizes, int n_in,
                              void* d_out, int out_size, void* d_ws, size_t ws_size,
                              hipStream_t stream)
{
    const float* x      = (const float*)d_in[0];
    const float* qkv_w  = (const float*)d_in[1];
    const float* proj_w = (const float*)d_in[2];
    const float* proj_b = (const float*)d_in[3];
    const float* qnw    = (const float*)d_in[4];
    const float* knw    = (const float*)d_in[5];

    char* ws = (char*)d_ws;
    __bf16* xb    = (__bf16*)(ws);                                 // 32 MB
    __bf16* wqkv  = (__bf16*)(ws + 33554432);                      // 6 MB
    __bf16* wproj = (__bf16*)(ws + 33554432 + 6291456);            // 2 MB
    __bf16* qkv   = (__bf16*)(ws + 41943040);                      // 96 MB
    __bf16* ao    = (__bf16*)(ws + 41943040 + 100663296);          // 32 MB

    f2b_kernel<<<2048, 256, 0, stream>>>((const float4*)x,      (bf16x4*)xb,    16777216 / 4);
    f2b_kernel<<<2048, 256, 0, stream>>>((const float4*)qkv_w,  (bf16x4*)wqkv,  3145728 / 4);
    f2b_kernel<<<1024, 256, 0, stream>>>((const float4*)proj_w, (bf16x4*)wproj, 1048576 / 4);

    gemm_bt<<<dim3(24, 128), 256, 0, stream>>>(xb, wqkv, nullptr, nullptr, qkv, 16384, 3072, 1024);
    rmsnorm_kernel<<<16384, 256, 0, stream>>>(qkv, qnw, knw);
    attn_kernel<<<dim3(16, 16, 16), 256, 0, stream>>>(qkv, ao);
    gemm_bt<<<dim3(8, 128), 256, 0, stream>>>(ao, wproj, proj_b, (float*)d_out, nullptr, 16384, 1024, 1024);
}